// Round 13
// baseline (217.304 us; speedup 1.0000x reference)
//
#include <hip/hip_runtime.h>
#include <hip/hip_bf16.h>
#include <stdint.h>

// Shapes: N=32, CIN=COUT=64, T=256, V=25, K3=3, G=8
// GCN folded to one GEMM: M=1600 (m=w*64+c), K=1600 (k=cin*25+v), N=8192 (n,t)
//   residual (+x) folded into U's diagonal: U[w*64+c][c*25+w] += 1
// k_prep: FUSED (2961 blocks), xt blocks FIRST so U-phase traffic evicts
//   part of xb's dirty L2 set during prep, not during gemm (R10-confirmed).
// k_gemm R13: 256m x 128n tile, 512 threads = 8 waves, each wave owns
//   64m x 64n as a 2x2 quad of 32x32 tiles using mfma_f32_32x32x16_bf16.
//   Rationale (R12 PMC): per wave per K-step, 20 ds_read_b128 (~240cy) vs
//   32 MFMA (~155cy) -> LDS-read-bound. 32x32 quad: 16 reads (~192cy) vs
//   16 MFMA (~128cy). Same staging/swizzle/LDS/grid as R12.
//   C layout (guide, HW-verified m74/m101): col=lane&31,
//   row=(reg&3)+8*(reg>>2)+4*(lane>>5).
// k_tcn: TB=16, 512 blocks, 80KB LDS, dual accumulators + 2-phase staging
//   (R9/R10 wins). Non-swapped epilogue (R6: coalescing beats vector width).
//   OOB window rows read from U's pad rows (zeroed by k_prep every call)

typedef const float* fp;
typedef __attribute__((ext_vector_type(8))) short short8;    // 8 bf16 (4 VGPRs)
typedef __attribute__((ext_vector_type(4))) float floatx4;   // 16x16 MFMA acc
typedef __attribute__((ext_vector_type(16))) float floatx16; // 32x32 MFMA acc

__device__ __forceinline__ float us2f(unsigned int u){
  union { unsigned int i; float f; } c; c.i = u << 16; return c.f;
}
__device__ __forceinline__ unsigned short f2us(float f){
  __hip_bfloat16 h = __float2bfloat16(f);
  return *reinterpret_cast<unsigned short*>(&h);
}
__device__ __forceinline__ void gload_lds16(const void* g, void* l){
  __builtin_amdgcn_global_load_lds(
      (const __attribute__((address_space(1))) void*)g,
      (__attribute__((address_space(3))) void*)l, 16, 0, 0);
}

// ---------------- workspace layout (bytes) ----------------
// cbe   fp32 [64]           @ 117504    (256)
// cwetb bf16 [64][9][64]    @ 117760    (73728)
// biasU fp32 [1600]         @ 191488    (6400)
// U     bf16 [1792][1600]   @ 197888    (5734400)  rows 1600+ = zero page
// xb    bf16 [32][256][1600]@ 5932288   (26214400)
// yb    bf16 [32][256][1600]@ 32146688  (26214400)   total ~58.4 MB

// ---------------- fused prep ----------------
// blocks [0,1024): x -> xb bf16 transpose (FIRST: xb dirty lines get
//                  evicted/written-back during the U phase below)
// blocks [1024,2816): U row m = bid-1024 (+ biasU), pad rows zeroed
// blocks [2816,2961): cwetb (36864) + cbe (64)  (last: L2-hot for k_tcn)
__global__ __launch_bounds__(256) void k_prep(
    fp x, fp A, fp W, fp b, fp g0, fp b0, fp g1, fp b1,
    fp cw, fp cb, fp g2, fp b2,
    unsigned short* U, float* biasU, unsigned short* xb,
    float* cbe, unsigned short* cwetb)
{
  int bid = blockIdx.x, tid = threadIdx.x;
  const float inv_s = rsqrtf(1.0f + 1e-5f);
  __shared__ __align__(16) char smemraw[26624];   // union: xt needs 26 KB

  if (bid < 1024) {                     // ---- x -> xb transpose ----
    int n = bid >> 5, tb = bid & 31, t0 = tb*8;
    unsigned short* xs = (unsigned short*)smemraw;  // [64*8][26]
    // x c-slab is 200 contiguous floats (8t x 25v): float4 loads
    for (int e4 = tid; e4 < 3200; e4 += 256) {
      int c = e4 / 50, r4 = (e4 - c*50)*4;
      floatx4 xv = *(const floatx4*)(x + (long long)(n*64 + c)*6400 + t0*25 + r4);
      int tt = r4 / 25, v = r4 - tt*25;
      xs[(c*8 + tt)*26 + v] = f2us(xv.x); if (++v == 25){v = 0; tt++;}
      xs[(c*8 + tt)*26 + v] = f2us(xv.y); if (++v == 25){v = 0; tt++;}
      xs[(c*8 + tt)*26 + v] = f2us(xv.z); if (++v == 25){v = 0; tt++;}
      xs[(c*8 + tt)*26 + v] = f2us(xv.w);
    }
    __syncthreads();
    for (int e4 = tid; e4 < 3200; e4 += 256) {      // ushort4 stores
      int base = e4 * 4;
      int tt = base / 1600, q0 = base - tt*1600;
      int c = q0 / 25, v = q0 - c*25;
      ushort4 pk;
      pk.x = xs[(c*8 + tt)*26 + v]; if (++v == 25){v = 0; c++;}
      pk.y = xs[(c*8 + tt)*26 + v]; if (++v == 25){v = 0; c++;}
      pk.z = xs[(c*8 + tt)*26 + v]; if (++v == 25){v = 0; c++;}
      pk.w = xs[(c*8 + tt)*26 + v];
      *(ushort4*)(xb + (long long)(n*256 + t0 + tt)*1600 + q0) = pk;
    }
    return;
  }

  if (bid < 2816) {                     // ---- U rows ----
    int m = bid - 1024;
    if (m >= 1600) {                    // zero-pad rows (k_tcn zero page)
      if (tid < 200) {
        short8 z = (short8){0,0,0,0,0,0,0,0};
        *(short8*)(U + (long long)m*1600 + tid*8) = z;
      }
      return;
    }
    float* nAL   = (float*)smemraw;          // 75 floats
    float* WeffL = (float*)(smemraw + 512);  // 192 floats
    float* cs3   = (float*)(smemraw + 1408); // 3 floats
    int c = m & 63, w = m >> 6, g = c & 7;
    if (tid < 75) {                     // raw A column w for (kk,g)
      int kk = tid / 25, vv = tid % 25;
      nAL[tid] = A[((kk*8 + g)*25 + vv)*25 + w];
    }
    if (tid < 192) {                    // W col c scaled by folded BN0 gain
      int kk = tid >> 6, cin = tid & 63;
      WeffL[tid] = W[cin*192 + kk*64 + c] * (g0[kk*64 + c] * inv_s);
    }
    __syncthreads();
    if (tid < 3) {                      // column sums -> denominators
      float s = 0.f;
      for (int vv = 0; vv < 25; vv++) s += nAL[tid*25 + vv];
      cs3[tid] = s + 0.001f;
    }
    __syncthreads();
    if (tid < 75) nAL[tid] = nAL[tid] / cs3[tid/25];
    __syncthreads();
    float s1 = g1[c] * inv_s;
    if (tid < 200) {                    // 8 consecutive k per thread
      int k0 = tid * 8;
      short8 pk;
      #pragma unroll
      for (int q = 0; q < 8; q++) {
        int k = k0 + q;
        int cin = k / 25, vv = k - cin*25;
        float acc = WeffL[cin]       * nAL[vv]
                  + WeffL[64 + cin]  * nAL[25 + vv]
                  + WeffL[128 + cin] * nAL[50 + vv];
        acc *= s1;
        if (cin == c && vv == w) acc += 1.0f;  // residual -> diagonal
        pk[q] = (short)f2us(acc);
      }
      *(short8*)(U + (long long)m*1600 + k0) = pk;
    }
    if (tid == 0) {
      float acc = 0.f;
      for (int kk = 0; kk < 3; kk++) {
        int d = kk*64 + c;
        float be = b[d] * (g0[d] * inv_s) + b0[d];
        for (int v = 0; v < 25; v++) acc += be * nAL[kk*25 + v];
      }
      biasU[m] = acc * s1 + b1[c];
    }
    return;
  }

  // ---- cwetb + cbe tail ----
  int gid = (bid - 2816)*256 + tid;
  if (gid < 36864) {                    // cwetb[o][j][i] bf16
    int o = gid / 576, r = gid % 576;
    int j = r / 64, i = r % 64;
    cwetb[gid] = f2us(cw[(o*64+i)*9 + j] * (g2[o] * inv_s));
    return;
  }
  gid -= 36864;
  if (gid < 64) {                       // cbe
    cbe[gid] = cb[gid] * (g2[gid] * inv_s) + b2[gid];
  }
}

// ---------------- GCN GEMM: 256m x 128n, 8 waves, 32x32 MFMA (R13) -------
// 448 blocks (7 bm x 64 bn), 512 threads. Wave (wm=wid>>1, wn=wid&1) owns
// 64m x 64n = 2x2 quad of 32x32 tiles. K-step 64 = 4 ks of 16.
// A-frag: lane holds A[row = mbase + (l&31)][k = ks*16 + (l>>5)*8 + j0..7];
// B-frag: B[k][col = tbase + (l&31)] same chunking -> both are 16B LDS reads
// at group ((ks*2 + (l>>5)) ^ (row&7)) of the XOR-swizzled tile.
__global__ __launch_bounds__(512, 4) void k_gemm(
    const unsigned short* U, const unsigned short* xb, const float* biasU,
    unsigned short* yb)
{
  int bm = blockIdx.x >> 6, bn = blockIdx.x & 63;   // 7 x 64
  int n = bn >> 1, t0 = (bn & 1) * 128;
  int tid = threadIdx.x, lane = tid & 63, wid = tid >> 6;
  int l31 = lane & 31, hw = lane >> 5, l7 = lane & 7;
  int wm = wid >> 1, wn = wid & 1;      // 4 x 2 wave grid

  __shared__ __align__(16) unsigned short As[256*64];  // 32 KB
  __shared__ __align__(16) unsigned short Bs[128*64];  // 16 KB

  const unsigned short* gA[4];
  const unsigned short* gB[2];
  unsigned short* lA[4];
  unsigned short* lB[2];
  #pragma unroll
  for (int it = 0; it < 4; it++) {
    int e = it*512 + tid;
    int row = e >> 3, li = e & 7;
    int kcol = (li ^ (row & 7)) * 8;       // XOR swizzle on global source side
    gA[it] = U + (long long)(bm*256 + row)*1600 + kcol;
    lA[it] = As + e*8;
  }
  #pragma unroll
  for (int it = 0; it < 2; it++) {
    int e = it*512 + tid;
    int row = e >> 3, li = e & 7;
    int kcol = (li ^ (row & 7)) * 8;
    gB[it] = xb + (long long)(n*256 + t0 + row)*1600 + kcol;
    lB[it] = Bs + e*8;
  }

  floatx16 acc[2][2];
  #pragma unroll
  for (int i = 0; i < 2; i++)
    #pragma unroll
    for (int j = 0; j < 2; j++)
      #pragma unroll
      for (int q = 0; q < 16; q++) acc[i][j][q] = 0.f;

  for (int kc = 0; kc < 25; kc++) {
    #pragma unroll
    for (int it = 0; it < 4; it++) gload_lds16(gA[it] + kc*64, lA[it]);
    #pragma unroll
    for (int it = 0; it < 2; it++) gload_lds16(gB[it] + kc*64, lB[it]);
    __syncthreads();
    #pragma unroll
    for (int ks = 0; ks < 4; ks++) {
      int cg = ((ks*2 + hw) ^ l7) * 8;     // un-swizzle at read (row&7 == l7)
      short8 af[2], bf[2];
      #pragma unroll
      for (int i = 0; i < 2; i++)
        af[i] = *(const short8*)(As + (wm*64 + i*32 + l31)*64 + cg);
      #pragma unroll
      for (int j = 0; j < 2; j++)
        bf[j] = *(const short8*)(Bs + (wn*64 + j*32 + l31)*64 + cg);
      #pragma unroll
      for (int i = 0; i < 2; i++)
        #pragma unroll
        for (int j = 0; j < 2; j++)
          acc[i][j] = __builtin_amdgcn_mfma_f32_32x32x16_bf16(af[i], bf[j], acc[i][j], 0, 0, 0);
    }
    __syncthreads();
  }

  // epilogue: C layout col=lane&31 (t), row=(reg&3)+8*(reg>>2)+4*hw (m)
  #pragma unroll
  for (int i = 0; i < 2; i++) {
    #pragma unroll
    for (int j = 0; j < 2; j++) {
      int t = t0 + wn*64 + j*32 + l31;
      #pragma unroll
      for (int q = 0; q < 4; q++) {
        int m4 = bm*256 + wm*64 + i*32 + hw*4 + q*8;
        if (m4 >= 1600) continue;
        float4 bu = *(const float4*)(biasU + m4);
        ushort4 pk;
        pk.x = f2us(fmaxf(acc[i][j][q*4+0] + bu.x, 0.f));
        pk.y = f2us(fmaxf(acc[i][j][q*4+1] + bu.y, 0.f));
        pk.z = f2us(fmaxf(acc[i][j][q*4+2] + bu.z, 0.f));
        pk.w = f2us(fmaxf(acc[i][j][q*4+3] + bu.w, 0.f));
        *(ushort4*)(yb + (long long)(n*256 + t)*1600 + m4) = pk;
      }
    }
  }
}

// ---------------- TCN as MFMA: TB=16, 512 blocks, dual-acc, 2-phase ------
// 8 waves share one 80 KB window (600 rows = 24t x 25v, pad to 640);
// wave pair (p, p+4) owns o-strip p*16 and splits the 25 col-tiles
// even/odd. Staging via global_load_lds; OOB rows from zpg.
// Phase split: stage rows<384 -> barrier -> issue rows 384-639 + compute
// tiles 0-10 (max row 375, disjoint from in-flight DMA) -> barrier ->
// tiles 11-24. Dual accumulators halve the MFMA dep chain.
__global__ __launch_bounds__(512) void k_tcn(
    const unsigned short* yb, const unsigned short* cwetb, const float* cbe,
    fp x, const unsigned short* zpg, float* out)
{
  int n = blockIdx.x >> 4, tb = blockIdx.x & 15, t0 = tb*16;
  int tid = threadIdx.x, lane = tid & 63, wid = tid >> 6;
  int l15 = lane & 15, grp = lane >> 4;
  __shared__ __align__(16) unsigned short ys[5120*8];  // 81920 B (600 rows + pad)

  #pragma unroll
  for (int it = 0; it < 6; it++) {        // chunk 1: rows < 384
    int e = it*512 + tid;
    int row = e >> 3, li = e & 7;
    int rt = row / 25, v = row - rt*25;
    int tg = t0 - 4 + rt;
    int sli = li ^ (row & 7);             // fetch swizzled i-group
    bool ok = (tg >= 0) && (tg < 256);
    const unsigned short* src = ok
      ? yb + ((long long)(n*256 + tg)*1600 + v*64 + sli*8)
      : zpg + li*8;
    gload_lds16(src, ys + e*8);           // linear LDS deposit
  }

  // A-frags: conv weights in registers, o-strip p = wid&3, half h = wid>>2
  int p = wid & 3, h = wid >> 2;
  int o0 = p * 16;
  int o = o0 + l15;
  short8 af[9][2];
  #pragma unroll
  for (int j = 0; j < 9; j++) {
    af[j][0] = *(const short8*)(cwetb + ((o*9 + j)*64 + grp*8));
    af[j][1] = *(const short8*)(cwetb + ((o*9 + j)*64 + 32 + grp*8));
  }
  float4 cb4 = *(const float4*)(cbe + o0 + grp*4);
  __syncthreads();                        // chunk 1 landed

  #pragma unroll
  for (int it = 6; it < 10; it++) {       // chunk 2: rows 384-639 (in flight)
    int e = it*512 + tid;
    int row = e >> 3, li = e & 7;
    int rt = row / 25, v = row - rt*25;
    int tg = t0 - 4 + rt;
    int sli = li ^ (row & 7);
    bool ok = (row < 600) && (tg >= 0) && (tg < 256);
    const unsigned short* src = ok
      ? yb + ((long long)(n*256 + tg)*1600 + v*64 + sli*8)
      : zpg + li*8;
    gload_lds16(src, ys + e*8);
  }

  #pragma unroll 1
  for (int phase = 0; phase < 2; phase++) {
    int tstart = phase ? (12 - h) : h;    // phase0: tiles<=10; phase1: 11-24
    int tend   = phase ? 25 : 11;
    for (int tile = tstart; tile < tend; tile += 2) {
      int colb = tile*16 + l15;
      floatx4 accA = (floatx4){0.f,0.f,0.f,0.f};
      floatx4 accB = (floatx4){0.f,0.f,0.f,0.f};
      #pragma unroll
      for (int j = 0; j < 9; j++) {
        int row = colb + 25*j;
        int r7 = row & 7;
        const unsigned short* rb = ys + row*64;
        short8 b0 = *(const short8*)(rb + ((grp     ^ r7))*8);
        short8 b1 = *(const short8*)(rb + (((4+grp) ^ r7))*8);
        if (j & 1) {
          accB = __builtin_amdgcn_mfma_f32_16x16x32_bf16(af[j][0], b0, accB, 0, 0, 0);
          accB = __builtin_amdgcn_mfma_f32_16x16x32_bf16(af[j][1], b1, accB, 0, 0, 0);
        } else {
          accA = __builtin_amdgcn_mfma_f32_16x16x32_bf16(af[j][0], b0, accA, 0, 0, 0);
          accA = __builtin_amdgcn_mfma_f32_16x16x32_bf16(af[j][1], b1, accA, 0, 0, 0);
        }
      }
      if (colb < 400) {
        int tt = colb / 25, v = colb - tt*25, t = t0 + tt;
        #pragma unroll
        for (int r = 0; r < 4; r++) {
          int oo = o0 + grp*4 + r;
          float val = accA[r] + accB[r] + ((const float*)&cb4)[r]
                    + x[((n*64 + oo)*256 + t)*25 + v];
          out[((n*64 + oo)*256 + t)*25 + v] = fmaxf(val, 0.f);
        }
      }
    }
    if (phase == 0) __syncthreads();      // chunk 2 landed
  }
}

extern "C" void kernel_launch(void* const* d_in, const int* in_sizes, int n_in,
                              void* d_out, int out_size, void* d_ws, size_t ws_size,
                              hipStream_t stream)
{
  fp x  = (fp)d_in[0];
  fp A  = (fp)d_in[1];
  fp W  = (fp)d_in[2];
  fp b  = (fp)d_in[3];
  fp g0 = (fp)d_in[4];
  fp b0 = (fp)d_in[5];
  fp g1 = (fp)d_in[6];
  fp b1 = (fp)d_in[7];
  fp cw = (fp)d_in[8];
  fp cb = (fp)d_in[9];
  fp g2 = (fp)d_in[10];
  fp b2 = (fp)d_in[11];
  // d_in[12] = keep_prob == 1 -> DropBlocks identity.

  char* ws = (char*)d_ws;
  float*          cbe   = (float*)(ws + 117504);
  unsigned short* cwetb = (unsigned short*)(ws + 117760);
  float*          biasU = (float*)(ws + 191488);
  unsigned short* U     = (unsigned short*)(ws + 197888);
  unsigned short* xb    = (unsigned short*)(ws + 5932288);
  unsigned short* yb    = (unsigned short*)(ws + 32146688);
  const unsigned short* zpg = U + (long long)1600*1600;  // zeroed pad rows

  k_prep<<<2961, 256, 0, stream>>>(x, A, W, b, g0, b0, g1, b1, cw, cb, g2, b2,
                                   U, biasU, xb, cbe, cwetb);
  k_gemm<<<448, 512, 0, stream>>>(U, xb, biasU, yb);
  k_tcn<<<512, 512, 0, stream>>>(yb, cwetb, cbe, x, zpg, (float*)d_out);
}

// Round 14
// 216.650 us; speedup vs baseline: 1.0030x; 1.0030x over previous
//
#include <hip/hip_runtime.h>
#include <hip/hip_bf16.h>
#include <stdint.h>

// Shapes: N=32, CIN=COUT=64, T=256, V=25, K3=3, G=8
// GCN folded to one GEMM: M=1600 (m=w*64+c), K=1600 (k=cin*25+v), N=8192 (n,t)
//   residual (+x) folded into U's diagonal: U[w*64+c][c*25+w] += 1
// k_prep: FUSED (2961 blocks), xt blocks FIRST so U-phase traffic evicts
//   part of xb's dirty L2 set during prep, not during gemm (R10-confirmed).
// k_gemm R14: 256m x 128n tile, 512 thr = 8 waves (R12 geometry, 16x16 MFMA:
//   R13 lesson — 32x32 read key spreads on l>>5 only -> 5.7M bank conflicts)
//   + BK=32 DOUBLE-BUFFERED staging (T3-minimum): issue next K-slab DMA
//   BEFORE compute, one vmcnt(0)+barrier per step -> stage overlaps MFMA.
//   LDS (16+8)KB x2 = 48KB keeps 2 blocks/CU. k ascending -> bit-identical.
// k_tcn: TB=16, 512 blocks, 80KB LDS, dual accumulators + 2-phase staging
//   (R9/R10 wins). Non-swapped epilogue (R6: coalescing beats vector width).
//   OOB window rows read from U's pad rows (zeroed by k_prep every call)

typedef const float* fp;
typedef __attribute__((ext_vector_type(8))) short short8;   // 8 bf16 (4 VGPRs)
typedef __attribute__((ext_vector_type(4))) float floatx4;  // MFMA acc

__device__ __forceinline__ float us2f(unsigned int u){
  union { unsigned int i; float f; } c; c.i = u << 16; return c.f;
}
__device__ __forceinline__ unsigned short f2us(float f){
  __hip_bfloat16 h = __float2bfloat16(f);
  return *reinterpret_cast<unsigned short*>(&h);
}
__device__ __forceinline__ void gload_lds16(const void* g, void* l){
  __builtin_amdgcn_global_load_lds(
      (const __attribute__((address_space(1))) void*)g,
      (__attribute__((address_space(3))) void*)l, 16, 0, 0);
}

// ---------------- workspace layout (bytes) ----------------
// cbe   fp32 [64]           @ 117504    (256)
// cwetb bf16 [64][9][64]    @ 117760    (73728)
// biasU fp32 [1600]         @ 191488    (6400)
// U     bf16 [1792][1600]   @ 197888    (5734400)  rows 1600+ = zero page
// xb    bf16 [32][256][1600]@ 5932288   (26214400)
// yb    bf16 [32][256][1600]@ 32146688  (26214400)   total ~58.4 MB

// ---------------- fused prep ----------------
// blocks [0,1024): x -> xb bf16 transpose (FIRST: xb dirty lines get
//                  evicted/written-back during the U phase below)
// blocks [1024,2816): U row m = bid-1024 (+ biasU), pad rows zeroed
// blocks [2816,2961): cwetb (36864) + cbe (64)  (last: L2-hot for k_tcn)
__global__ __launch_bounds__(256) void k_prep(
    fp x, fp A, fp W, fp b, fp g0, fp b0, fp g1, fp b1,
    fp cw, fp cb, fp g2, fp b2,
    unsigned short* U, float* biasU, unsigned short* xb,
    float* cbe, unsigned short* cwetb)
{
  int bid = blockIdx.x, tid = threadIdx.x;
  const float inv_s = rsqrtf(1.0f + 1e-5f);
  __shared__ __align__(16) char smemraw[26624];   // union: xt needs 26 KB

  if (bid < 1024) {                     // ---- x -> xb transpose ----
    int n = bid >> 5, tb = bid & 31, t0 = tb*8;
    unsigned short* xs = (unsigned short*)smemraw;  // [64*8][26]
    // x c-slab is 200 contiguous floats (8t x 25v): float4 loads
    for (int e4 = tid; e4 < 3200; e4 += 256) {
      int c = e4 / 50, r4 = (e4 - c*50)*4;
      floatx4 xv = *(const floatx4*)(x + (long long)(n*64 + c)*6400 + t0*25 + r4);
      int tt = r4 / 25, v = r4 - tt*25;
      xs[(c*8 + tt)*26 + v] = f2us(xv.x); if (++v == 25){v = 0; tt++;}
      xs[(c*8 + tt)*26 + v] = f2us(xv.y); if (++v == 25){v = 0; tt++;}
      xs[(c*8 + tt)*26 + v] = f2us(xv.z); if (++v == 25){v = 0; tt++;}
      xs[(c*8 + tt)*26 + v] = f2us(xv.w);
    }
    __syncthreads();
    for (int e4 = tid; e4 < 3200; e4 += 256) {      // ushort4 stores
      int base = e4 * 4;
      int tt = base / 1600, q0 = base - tt*1600;
      int c = q0 / 25, v = q0 - c*25;
      ushort4 pk;
      pk.x = xs[(c*8 + tt)*26 + v]; if (++v == 25){v = 0; c++;}
      pk.y = xs[(c*8 + tt)*26 + v]; if (++v == 25){v = 0; c++;}
      pk.z = xs[(c*8 + tt)*26 + v]; if (++v == 25){v = 0; c++;}
      pk.w = xs[(c*8 + tt)*26 + v];
      *(ushort4*)(xb + (long long)(n*256 + t0 + tt)*1600 + q0) = pk;
    }
    return;
  }

  if (bid < 2816) {                     // ---- U rows ----
    int m = bid - 1024;
    if (m >= 1600) {                    // zero-pad rows (k_tcn zero page)
      if (tid < 200) {
        short8 z = (short8){0,0,0,0,0,0,0,0};
        *(short8*)(U + (long long)m*1600 + tid*8) = z;
      }
      return;
    }
    float* nAL   = (float*)smemraw;          // 75 floats
    float* WeffL = (float*)(smemraw + 512);  // 192 floats
    float* cs3   = (float*)(smemraw + 1408); // 3 floats
    int c = m & 63, w = m >> 6, g = c & 7;
    if (tid < 75) {                     // raw A column w for (kk,g)
      int kk = tid / 25, vv = tid % 25;
      nAL[tid] = A[((kk*8 + g)*25 + vv)*25 + w];
    }
    if (tid < 192) {                    // W col c scaled by folded BN0 gain
      int kk = tid >> 6, cin = tid & 63;
      WeffL[tid] = W[cin*192 + kk*64 + c] * (g0[kk*64 + c] * inv_s);
    }
    __syncthreads();
    if (tid < 3) {                      // column sums -> denominators
      float s = 0.f;
      for (int vv = 0; vv < 25; vv++) s += nAL[tid*25 + vv];
      cs3[tid] = s + 0.001f;
    }
    __syncthreads();
    if (tid < 75) nAL[tid] = nAL[tid] / cs3[tid/25];
    __syncthreads();
    float s1 = g1[c] * inv_s;
    if (tid < 200) {                    // 8 consecutive k per thread
      int k0 = tid * 8;
      short8 pk;
      #pragma unroll
      for (int q = 0; q < 8; q++) {
        int k = k0 + q;
        int cin = k / 25, vv = k - cin*25;
        float acc = WeffL[cin]       * nAL[vv]
                  + WeffL[64 + cin]  * nAL[25 + vv]
                  + WeffL[128 + cin] * nAL[50 + vv];
        acc *= s1;
        if (cin == c && vv == w) acc += 1.0f;  // residual -> diagonal
        pk[q] = (short)f2us(acc);
      }
      *(short8*)(U + (long long)m*1600 + k0) = pk;
    }
    if (tid == 0) {
      float acc = 0.f;
      for (int kk = 0; kk < 3; kk++) {
        int d = kk*64 + c;
        float be = b[d] * (g0[d] * inv_s) + b0[d];
        for (int v = 0; v < 25; v++) acc += be * nAL[kk*25 + v];
      }
      biasU[m] = acc * s1 + b1[c];
    }
    return;
  }

  // ---- cwetb + cbe tail ----
  int gid = (bid - 2816)*256 + tid;
  if (gid < 36864) {                    // cwetb[o][j][i] bf16
    int o = gid / 576, r = gid % 576;
    int j = r / 64, i = r % 64;
    cwetb[gid] = f2us(cw[(o*64+i)*9 + j] * (g2[o] * inv_s));
    return;
  }
  gid -= 36864;
  if (gid < 64) {                       // cbe
    cbe[gid] = cb[gid] * (g2[gid] * inv_s) + b2[gid];
  }
}

// ---------------- GCN GEMM: 256m x 128n, BK=32 double-buffer (R14) -------
// 448 blocks (7 bm x 64 bn), 512 threads = 8 waves, wave owns 32m x 128n
// (R12's verified 16x16 read geometry). 50 K-steps of 32; per step:
//   issue next-slab DMA (3 chunks) -> compute current -> vmcnt(0)+barrier.
// Buffer written at step kc was last read at kc-1, whose end-of-step
// barrier all waves crossed -> no race. k ascending -> bit-identical.
__global__ __launch_bounds__(512, 4) void k_gemm(
    const unsigned short* U, const unsigned short* xb, const float* biasU,
    unsigned short* yb)
{
  int bm = blockIdx.x >> 6, bn = blockIdx.x & 63;   // 7 x 64
  int n = bn >> 1, t0 = (bn & 1) * 128;
  int tid = threadIdx.x, lane = tid & 63, wid = tid >> 6;
  int l15 = lane & 15, grp = lane >> 4;

  __shared__ __align__(16) unsigned short As[2][256*32];  // 2 x 16 KB
  __shared__ __align__(16) unsigned short Bs[2][128*32];  // 2 x 8 KB

  // staging map (BK=32): row has 4 16B-chunks; chunk li stored at physical
  // position li, sourcing logical group (li ^ (row&3)) -> read logical g at
  // physical (g ^ (row&3)).
  const unsigned short* gA[2];
  const unsigned short* gB;
  int eA0 = tid, eA1 = 512 + tid;       // e in [0,1024)
  {
    int r0 = eA0 >> 2, l0 = eA0 & 3;
    int r1 = eA1 >> 2, l1 = eA1 & 3;
    gA[0] = U + (long long)(bm*256 + r0)*1600 + (l0 ^ (r0 & 3))*8;
    gA[1] = U + (long long)(bm*256 + r1)*1600 + (l1 ^ (r1 & 3))*8;
    int rb = tid >> 2, lb = tid & 3;
    gB = xb + (long long)(n*256 + t0 + rb)*1600 + (lb ^ (rb & 3))*8;
  }

  floatx4 acc[2][8];
  #pragma unroll
  for (int i = 0; i < 2; i++)
    #pragma unroll
    for (int j = 0; j < 8; j++) acc[i][j] = (floatx4){0.f,0.f,0.f,0.f};

  int colk = (grp ^ (l15 & 3)) * 8;     // un-swizzle (row&3 == l15&3 for all reads)

  // prologue: stage slab 0 into buf 0
  gload_lds16(gA[0], &As[0][eA0*8]);
  gload_lds16(gA[1], &As[0][eA1*8]);
  gload_lds16(gB,    &Bs[0][tid*8]);
  asm volatile("s_waitcnt vmcnt(0)" ::: "memory");
  __syncthreads();

  for (int kc = 0; kc < 50; kc++) {
    int cur = kc & 1, nxt = cur ^ 1;
    if (kc < 49) {                      // stage next slab BEFORE compute
      gload_lds16(gA[0] + (kc+1)*32, &As[nxt][eA0*8]);
      gload_lds16(gA[1] + (kc+1)*32, &As[nxt][eA1*8]);
      gload_lds16(gB    + (kc+1)*32, &Bs[nxt][tid*8]);
    }
    short8 af[2], bf[8];
    #pragma unroll
    for (int i = 0; i < 2; i++)
      af[i] = *(const short8*)(&As[cur][(wid*32 + i*16 + l15)*32 + colk]);
    #pragma unroll
    for (int j = 0; j < 8; j++)
      bf[j] = *(const short8*)(&Bs[cur][(j*16 + l15)*32 + colk]);
    #pragma unroll
    for (int i = 0; i < 2; i++)
      #pragma unroll
      for (int j = 0; j < 8; j++)
        acc[i][j] = __builtin_amdgcn_mfma_f32_16x16x32_bf16(af[i], bf[j], acc[i][j], 0, 0, 0);
    asm volatile("s_waitcnt vmcnt(0)" ::: "memory");
    __syncthreads();
  }

  #pragma unroll
  for (int i = 0; i < 2; i++) {
    int mbase = bm*256 + wid*32 + i*16 + grp*4;
    if (mbase >= 1600) continue;
    float4 bu = *(const float4*)(biasU + mbase);
    #pragma unroll
    for (int j = 0; j < 8; j++) {
      int col = j*16 + l15;
      int t = t0 + col;
      ushort4 pk;
      pk.x = f2us(fmaxf(acc[i][j][0] + bu.x, 0.f));
      pk.y = f2us(fmaxf(acc[i][j][1] + bu.y, 0.f));
      pk.z = f2us(fmaxf(acc[i][j][2] + bu.z, 0.f));
      pk.w = f2us(fmaxf(acc[i][j][3] + bu.w, 0.f));
      *(ushort4*)(yb + (long long)(n*256 + t)*1600 + mbase) = pk;
    }
  }
}

// ---------------- TCN as MFMA: TB=16, 512 blocks, dual-acc, 2-phase ------
// 8 waves share one 80 KB window (600 rows = 24t x 25v, pad to 640);
// wave pair (p, p+4) owns o-strip p*16 and splits the 25 col-tiles
// even/odd. Staging via global_load_lds; OOB rows from zpg.
// Phase split: stage rows<384 -> barrier -> issue rows 384-639 + compute
// tiles 0-10 (max row 375, disjoint from in-flight DMA) -> barrier ->
// tiles 11-24. Dual accumulators halve the MFMA dep chain.
__global__ __launch_bounds__(512) void k_tcn(
    const unsigned short* yb, const unsigned short* cwetb, const float* cbe,
    fp x, const unsigned short* zpg, float* out)
{
  int n = blockIdx.x >> 4, tb = blockIdx.x & 15, t0 = tb*16;
  int tid = threadIdx.x, lane = tid & 63, wid = tid >> 6;
  int l15 = lane & 15, grp = lane >> 4;
  __shared__ __align__(16) unsigned short ys[5120*8];  // 81920 B (600 rows + pad)

  #pragma unroll
  for (int it = 0; it < 6; it++) {        // chunk 1: rows < 384
    int e = it*512 + tid;
    int row = e >> 3, li = e & 7;
    int rt = row / 25, v = row - rt*25;
    int tg = t0 - 4 + rt;
    int sli = li ^ (row & 7);             // fetch swizzled i-group
    bool ok = (tg >= 0) && (tg < 256);
    const unsigned short* src = ok
      ? yb + ((long long)(n*256 + tg)*1600 + v*64 + sli*8)
      : zpg + li*8;
    gload_lds16(src, ys + e*8);           // linear LDS deposit
  }

  // A-frags: conv weights in registers, o-strip p = wid&3, half h = wid>>2
  int p = wid & 3, h = wid >> 2;
  int o0 = p * 16;
  int o = o0 + l15;
  short8 af[9][2];
  #pragma unroll
  for (int j = 0; j < 9; j++) {
    af[j][0] = *(const short8*)(cwetb + ((o*9 + j)*64 + grp*8));
    af[j][1] = *(const short8*)(cwetb + ((o*9 + j)*64 + 32 + grp*8));
  }
  float4 cb4 = *(const float4*)(cbe + o0 + grp*4);
  __syncthreads();                        // chunk 1 landed

  #pragma unroll
  for (int it = 6; it < 10; it++) {       // chunk 2: rows 384-639 (in flight)
    int e = it*512 + tid;
    int row = e >> 3, li = e & 7;
    int rt = row / 25, v = row - rt*25;
    int tg = t0 - 4 + rt;
    int sli = li ^ (row & 7);
    bool ok = (row < 600) && (tg >= 0) && (tg < 256);
    const unsigned short* src = ok
      ? yb + ((long long)(n*256 + tg)*1600 + v*64 + sli*8)
      : zpg + li*8;
    gload_lds16(src, ys + e*8);
  }

  #pragma unroll 1
  for (int phase = 0; phase < 2; phase++) {
    int tstart = phase ? (12 - h) : h;    // phase0: tiles<=10; phase1: 11-24
    int tend   = phase ? 25 : 11;
    for (int tile = tstart; tile < tend; tile += 2) {
      int colb = tile*16 + l15;
      floatx4 accA = (floatx4){0.f,0.f,0.f,0.f};
      floatx4 accB = (floatx4){0.f,0.f,0.f,0.f};
      #pragma unroll
      for (int j = 0; j < 9; j++) {
        int row = colb + 25*j;
        int r7 = row & 7;
        const unsigned short* rb = ys + row*64;
        short8 b0 = *(const short8*)(rb + ((grp     ^ r7))*8);
        short8 b1 = *(const short8*)(rb + (((4+grp) ^ r7))*8);
        if (j & 1) {
          accB = __builtin_amdgcn_mfma_f32_16x16x32_bf16(af[j][0], b0, accB, 0, 0, 0);
          accB = __builtin_amdgcn_mfma_f32_16x16x32_bf16(af[j][1], b1, accB, 0, 0, 0);
        } else {
          accA = __builtin_amdgcn_mfma_f32_16x16x32_bf16(af[j][0], b0, accA, 0, 0, 0);
          accA = __builtin_amdgcn_mfma_f32_16x16x32_bf16(af[j][1], b1, accA, 0, 0, 0);
        }
      }
      if (colb < 400) {
        int tt = colb / 25, v = colb - tt*25, t = t0 + tt;
        #pragma unroll
        for (int r = 0; r < 4; r++) {
          int oo = o0 + grp*4 + r;
          float val = accA[r] + accB[r] + ((const float*)&cb4)[r]
                    + x[((n*64 + oo)*256 + t)*25 + v];
          out[((n*64 + oo)*256 + t)*25 + v] = fmaxf(val, 0.f);
        }
      }
    }
    if (phase == 0) __syncthreads();      // chunk 2 landed
  }
}

extern "C" void kernel_launch(void* const* d_in, const int* in_sizes, int n_in,
                              void* d_out, int out_size, void* d_ws, size_t ws_size,
                              hipStream_t stream)
{
  fp x  = (fp)d_in[0];
  fp A  = (fp)d_in[1];
  fp W  = (fp)d_in[2];
  fp b  = (fp)d_in[3];
  fp g0 = (fp)d_in[4];
  fp b0 = (fp)d_in[5];
  fp g1 = (fp)d_in[6];
  fp b1 = (fp)d_in[7];
  fp cw = (fp)d_in[8];
  fp cb = (fp)d_in[9];
  fp g2 = (fp)d_in[10];
  fp b2 = (fp)d_in[11];
  // d_in[12] = keep_prob == 1 -> DropBlocks identity.

  char* ws = (char*)d_ws;
  float*          cbe   = (float*)(ws + 117504);
  unsigned short* cwetb = (unsigned short*)(ws + 117760);
  float*          biasU = (float*)(ws + 191488);
  unsigned short* U     = (unsigned short*)(ws + 197888);
  unsigned short* xb    = (unsigned short*)(ws + 5932288);
  unsigned short* yb    = (unsigned short*)(ws + 32146688);
  const unsigned short* zpg = U + (long long)1600*1600;  // zeroed pad rows

  k_prep<<<2961, 256, 0, stream>>>(x, A, W, b, g0, b0, g1, b1, cw, cb, g2, b2,
                                   U, biasU, xb, cbe, cwetb);
  k_gemm<<<448, 512, 0, stream>>>(U, xb, biasU, yb);
  k_tcn<<<512, 512, 0, stream>>>(yb, cwetb, cbe, x, zpg, (float*)d_out);
}

// Round 15
// 205.952 us; speedup vs baseline: 1.0551x; 1.0519x over previous
//
#include <hip/hip_runtime.h>
#include <hip/hip_bf16.h>
#include <stdint.h>

// Shapes: N=32, CIN=COUT=64, T=256, V=25, K3=3, G=8
// GCN folded to one GEMM: M=1600 (m=w*64+c), K=1600 (k=cin*25+v), N=8192 (n,t)
//   residual (+x) folded into U's diagonal: U[w*64+c][c*25+w] += 1
// k_prep: FUSED (2961 blocks), xt blocks FIRST so U-phase traffic evicts
//   part of xb's dirty L2 set during prep, not during gemm (R10-confirmed:
//   gemm WRITE 60->45MB). NT stores strictly worse (R7/R8).
// k_gemm (R12, session best): 256m x 128n tile, 512 threads = 8 waves,
//   wave owns 32m x 128n. 2-barrier loop, BK=64, XOR-swizzled staging,
//   conflict-free 16x16 reads. Grid ledger of failed alternatives:
//   8-phase 67-71us (R1/R2: 1 blk/CU no overlap; XCD swizzle broke B-panel
//   L2 affinity), 128^2 63us (R11: halved MFMA-per-barrier), 32x32 MFMA
//   63.6us (R13: read key on l>>5 only -> 5.7M bank conflicts), BK=32 dbuf
//   62.5us (R14: 2-bit XOR key -> 7.2M conflicts). bid%8 = bn%8 keeps
//   B-panel reuse XCD-local.
// k_tcn: TB=16, 512 blocks, 80KB LDS, dual accumulators + 2-phase staging
//   (R9/R10 wins). Non-swapped epilogue (R6: coalescing beats vector width).
//   OOB window rows read from U's pad rows (zeroed by k_prep every call)

typedef const float* fp;
typedef __attribute__((ext_vector_type(8))) short short8;   // 8 bf16 (4 VGPRs)
typedef __attribute__((ext_vector_type(4))) float floatx4;  // MFMA acc

__device__ __forceinline__ float us2f(unsigned int u){
  union { unsigned int i; float f; } c; c.i = u << 16; return c.f;
}
__device__ __forceinline__ unsigned short f2us(float f){
  __hip_bfloat16 h = __float2bfloat16(f);
  return *reinterpret_cast<unsigned short*>(&h);
}
__device__ __forceinline__ void gload_lds16(const void* g, void* l){
  __builtin_amdgcn_global_load_lds(
      (const __attribute__((address_space(1))) void*)g,
      (__attribute__((address_space(3))) void*)l, 16, 0, 0);
}

// ---------------- workspace layout (bytes) ----------------
// cbe   fp32 [64]           @ 117504    (256)
// cwetb bf16 [64][9][64]    @ 117760    (73728)
// biasU fp32 [1600]         @ 191488    (6400)
// U     bf16 [1792][1600]   @ 197888    (5734400)  rows 1600+ = zero page
// xb    bf16 [32][256][1600]@ 5932288   (26214400)
// yb    bf16 [32][256][1600]@ 32146688  (26214400)   total ~58.4 MB

// ---------------- fused prep ----------------
// blocks [0,1024): x -> xb bf16 transpose (FIRST: xb dirty lines get
//                  evicted/written-back during the U phase below)
// blocks [1024,2816): U row m = bid-1024 (+ biasU), pad rows zeroed
// blocks [2816,2961): cwetb (36864) + cbe (64)  (last: L2-hot for k_tcn)
__global__ __launch_bounds__(256) void k_prep(
    fp x, fp A, fp W, fp b, fp g0, fp b0, fp g1, fp b1,
    fp cw, fp cb, fp g2, fp b2,
    unsigned short* U, float* biasU, unsigned short* xb,
    float* cbe, unsigned short* cwetb)
{
  int bid = blockIdx.x, tid = threadIdx.x;
  const float inv_s = rsqrtf(1.0f + 1e-5f);
  __shared__ __align__(16) char smemraw[26624];   // union: xt needs 26 KB

  if (bid < 1024) {                     // ---- x -> xb transpose ----
    int n = bid >> 5, tb = bid & 31, t0 = tb*8;
    unsigned short* xs = (unsigned short*)smemraw;  // [64*8][26]
    // x c-slab is 200 contiguous floats (8t x 25v): float4 loads
    for (int e4 = tid; e4 < 3200; e4 += 256) {
      int c = e4 / 50, r4 = (e4 - c*50)*4;
      floatx4 xv = *(const floatx4*)(x + (long long)(n*64 + c)*6400 + t0*25 + r4);
      int tt = r4 / 25, v = r4 - tt*25;
      xs[(c*8 + tt)*26 + v] = f2us(xv.x); if (++v == 25){v = 0; tt++;}
      xs[(c*8 + tt)*26 + v] = f2us(xv.y); if (++v == 25){v = 0; tt++;}
      xs[(c*8 + tt)*26 + v] = f2us(xv.z); if (++v == 25){v = 0; tt++;}
      xs[(c*8 + tt)*26 + v] = f2us(xv.w);
    }
    __syncthreads();
    for (int e4 = tid; e4 < 3200; e4 += 256) {      // ushort4 stores
      int base = e4 * 4;
      int tt = base / 1600, q0 = base - tt*1600;
      int c = q0 / 25, v = q0 - c*25;
      ushort4 pk;
      pk.x = xs[(c*8 + tt)*26 + v]; if (++v == 25){v = 0; c++;}
      pk.y = xs[(c*8 + tt)*26 + v]; if (++v == 25){v = 0; c++;}
      pk.z = xs[(c*8 + tt)*26 + v]; if (++v == 25){v = 0; c++;}
      pk.w = xs[(c*8 + tt)*26 + v];
      *(ushort4*)(xb + (long long)(n*256 + t0 + tt)*1600 + q0) = pk;
    }
    return;
  }

  if (bid < 2816) {                     // ---- U rows ----
    int m = bid - 1024;
    if (m >= 1600) {                    // zero-pad rows (k_tcn zero page)
      if (tid < 200) {
        short8 z = (short8){0,0,0,0,0,0,0,0};
        *(short8*)(U + (long long)m*1600 + tid*8) = z;
      }
      return;
    }
    float* nAL   = (float*)smemraw;          // 75 floats
    float* WeffL = (float*)(smemraw + 512);  // 192 floats
    float* cs3   = (float*)(smemraw + 1408); // 3 floats
    int c = m & 63, w = m >> 6, g = c & 7;
    if (tid < 75) {                     // raw A column w for (kk,g)
      int kk = tid / 25, vv = tid % 25;
      nAL[tid] = A[((kk*8 + g)*25 + vv)*25 + w];
    }
    if (tid < 192) {                    // W col c scaled by folded BN0 gain
      int kk = tid >> 6, cin = tid & 63;
      WeffL[tid] = W[cin*192 + kk*64 + c] * (g0[kk*64 + c] * inv_s);
    }
    __syncthreads();
    if (tid < 3) {                      // column sums -> denominators
      float s = 0.f;
      for (int vv = 0; vv < 25; vv++) s += nAL[tid*25 + vv];
      cs3[tid] = s + 0.001f;
    }
    __syncthreads();
    if (tid < 75) nAL[tid] = nAL[tid] / cs3[tid/25];
    __syncthreads();
    float s1 = g1[c] * inv_s;
    if (tid < 200) {                    // 8 consecutive k per thread
      int k0 = tid * 8;
      short8 pk;
      #pragma unroll
      for (int q = 0; q < 8; q++) {
        int k = k0 + q;
        int cin = k / 25, vv = k - cin*25;
        float acc = WeffL[cin]       * nAL[vv]
                  + WeffL[64 + cin]  * nAL[25 + vv]
                  + WeffL[128 + cin] * nAL[50 + vv];
        acc *= s1;
        if (cin == c && vv == w) acc += 1.0f;  // residual -> diagonal
        pk[q] = (short)f2us(acc);
      }
      *(short8*)(U + (long long)m*1600 + k0) = pk;
    }
    if (tid == 0) {
      float acc = 0.f;
      for (int kk = 0; kk < 3; kk++) {
        int d = kk*64 + c;
        float be = b[d] * (g0[d] * inv_s) + b0[d];
        for (int v = 0; v < 25; v++) acc += be * nAL[kk*25 + v];
      }
      biasU[m] = acc * s1 + b1[c];
    }
    return;
  }

  // ---- cwetb + cbe tail ----
  int gid = (bid - 2816)*256 + tid;
  if (gid < 36864) {                    // cwetb[o][j][i] bf16
    int o = gid / 576, r = gid % 576;
    int j = r / 64, i = r % 64;
    cwetb[gid] = f2us(cw[(o*64+i)*9 + j] * (g2[o] * inv_s));
    return;
  }
  gid -= 36864;
  if (gid < 64) {                       // cbe
    cbe[gid] = cb[gid] * (g2[gid] * inv_s) + b2[gid];
  }
}

// ---------------- GCN GEMM: 256m x 128n, 8 waves (R12, session best) -----
// 448 blocks (7 bm x 64 bn), 512 threads = 8 waves, wave owns 32m x 128n.
// 48KB LDS -> 2 blocks/CU, ~16 waves/CU hide the 2-barrier drain (m114).
__global__ __launch_bounds__(512, 4) void k_gemm(
    const unsigned short* U, const unsigned short* xb, const float* biasU,
    unsigned short* yb)
{
  int bm = blockIdx.x >> 6, bn = blockIdx.x & 63;   // 7 x 64
  int n = bn >> 1, t0 = (bn & 1) * 128;
  int tid = threadIdx.x, lane = tid & 63, wid = tid >> 6;
  int l15 = lane & 15, grp = lane >> 4;

  __shared__ __align__(16) unsigned short As[256*64];  // 32 KB
  __shared__ __align__(16) unsigned short Bs[128*64];  // 16 KB

  const unsigned short* gA[4];
  const unsigned short* gB[2];
  unsigned short* lA[4];
  unsigned short* lB[2];
  #pragma unroll
  for (int it = 0; it < 4; it++) {
    int e = it*512 + tid;
    int row = e >> 3, li = e & 7;
    int kcol = (li ^ (row & 7)) * 8;       // XOR swizzle on global source side
    gA[it] = U + (long long)(bm*256 + row)*1600 + kcol;
    lA[it] = As + e*8;
  }
  #pragma unroll
  for (int it = 0; it < 2; it++) {
    int e = it*512 + tid;
    int row = e >> 3, li = e & 7;
    int kcol = (li ^ (row & 7)) * 8;
    gB[it] = xb + (long long)(n*256 + t0 + row)*1600 + kcol;
    lB[it] = Bs + e*8;
  }

  floatx4 acc[2][8];
  #pragma unroll
  for (int i = 0; i < 2; i++)
    #pragma unroll
    for (int j = 0; j < 8; j++) acc[i][j] = (floatx4){0.f,0.f,0.f,0.f};

  for (int kc = 0; kc < 25; kc++) {
    #pragma unroll
    for (int it = 0; it < 4; it++) gload_lds16(gA[it] + kc*64, lA[it]);
    #pragma unroll
    for (int it = 0; it < 2; it++) gload_lds16(gB[it] + kc*64, lB[it]);
    __syncthreads();
    #pragma unroll
    for (int ks = 0; ks < 2; ks++) {
      int colk = ((ks*4 + grp) ^ (l15 & 7)) * 8;   // un-swizzle at read
      short8 af[2], bf[8];
      #pragma unroll
      for (int i = 0; i < 2; i++)
        af[i] = *(const short8*)(As + (wid*32 + i*16 + l15)*64 + colk);
      #pragma unroll
      for (int j = 0; j < 8; j++)
        bf[j] = *(const short8*)(Bs + (j*16 + l15)*64 + colk);
      #pragma unroll
      for (int i = 0; i < 2; i++)
        #pragma unroll
        for (int j = 0; j < 8; j++)
          acc[i][j] = __builtin_amdgcn_mfma_f32_16x16x32_bf16(af[i], bf[j], acc[i][j], 0, 0, 0);
    }
    __syncthreads();
  }

  #pragma unroll
  for (int i = 0; i < 2; i++) {
    int mbase = bm*256 + wid*32 + i*16 + grp*4;
    if (mbase >= 1600) continue;
    float4 bu = *(const float4*)(biasU + mbase);
    #pragma unroll
    for (int j = 0; j < 8; j++) {
      int col = j*16 + l15;
      int t = t0 + col;
      ushort4 pk;
      pk.x = f2us(fmaxf(acc[i][j][0] + bu.x, 0.f));
      pk.y = f2us(fmaxf(acc[i][j][1] + bu.y, 0.f));
      pk.z = f2us(fmaxf(acc[i][j][2] + bu.z, 0.f));
      pk.w = f2us(fmaxf(acc[i][j][3] + bu.w, 0.f));
      *(ushort4*)(yb + (long long)(n*256 + t)*1600 + mbase) = pk;
    }
  }
}

// ---------------- TCN as MFMA: TB=16, 512 blocks, dual-acc, 2-phase ------
// 8 waves share one 80 KB window (600 rows = 24t x 25v, pad to 640);
// wave pair (p, p+4) owns o-strip p*16 and splits the 25 col-tiles
// even/odd. Staging via global_load_lds; OOB rows from zpg.
// Phase split: stage rows<384 -> barrier -> issue rows 384-639 + compute
// tiles 0-10 (max row 375, disjoint from in-flight DMA) -> barrier ->
// tiles 11-24. Dual accumulators halve the MFMA dep chain.
__global__ __launch_bounds__(512) void k_tcn(
    const unsigned short* yb, const unsigned short* cwetb, const float* cbe,
    fp x, const unsigned short* zpg, float* out)
{
  int n = blockIdx.x >> 4, tb = blockIdx.x & 15, t0 = tb*16;
  int tid = threadIdx.x, lane = tid & 63, wid = tid >> 6;
  int l15 = lane & 15, grp = lane >> 4;
  __shared__ __align__(16) unsigned short ys[5120*8];  // 81920 B (600 rows + pad)

  #pragma unroll
  for (int it = 0; it < 6; it++) {        // chunk 1: rows < 384
    int e = it*512 + tid;
    int row = e >> 3, li = e & 7;
    int rt = row / 25, v = row - rt*25;
    int tg = t0 - 4 + rt;
    int sli = li ^ (row & 7);             // fetch swizzled i-group
    bool ok = (tg >= 0) && (tg < 256);
    const unsigned short* src = ok
      ? yb + ((long long)(n*256 + tg)*1600 + v*64 + sli*8)
      : zpg + li*8;
    gload_lds16(src, ys + e*8);           // linear LDS deposit
  }

  // A-frags: conv weights in registers, o-strip p = wid&3, half h = wid>>2
  int p = wid & 3, h = wid >> 2;
  int o0 = p * 16;
  int o = o0 + l15;
  short8 af[9][2];
  #pragma unroll
  for (int j = 0; j < 9; j++) {
    af[j][0] = *(const short8*)(cwetb + ((o*9 + j)*64 + grp*8));
    af[j][1] = *(const short8*)(cwetb + ((o*9 + j)*64 + 32 + grp*8));
  }
  float4 cb4 = *(const float4*)(cbe + o0 + grp*4);
  __syncthreads();                        // chunk 1 landed

  #pragma unroll
  for (int it = 6; it < 10; it++) {       // chunk 2: rows 384-639 (in flight)
    int e = it*512 + tid;
    int row = e >> 3, li = e & 7;
    int rt = row / 25, v = row - rt*25;
    int tg = t0 - 4 + rt;
    int sli = li ^ (row & 7);
    bool ok = (row < 600) && (tg >= 0) && (tg < 256);
    const unsigned short* src = ok
      ? yb + ((long long)(n*256 + tg)*1600 + v*64 + sli*8)
      : zpg + li*8;
    gload_lds16(src, ys + e*8);
  }

  #pragma unroll 1
  for (int phase = 0; phase < 2; phase++) {
    int tstart = phase ? (12 - h) : h;    // phase0: tiles<=10; phase1: 11-24
    int tend   = phase ? 25 : 11;
    for (int tile = tstart; tile < tend; tile += 2) {
      int colb = tile*16 + l15;
      floatx4 accA = (floatx4){0.f,0.f,0.f,0.f};
      floatx4 accB = (floatx4){0.f,0.f,0.f,0.f};
      #pragma unroll
      for (int j = 0; j < 9; j++) {
        int row = colb + 25*j;
        int r7 = row & 7;
        const unsigned short* rb = ys + row*64;
        short8 b0 = *(const short8*)(rb + ((grp     ^ r7))*8);
        short8 b1 = *(const short8*)(rb + (((4+grp) ^ r7))*8);
        if (j & 1) {
          accB = __builtin_amdgcn_mfma_f32_16x16x32_bf16(af[j][0], b0, accB, 0, 0, 0);
          accB = __builtin_amdgcn_mfma_f32_16x16x32_bf16(af[j][1], b1, accB, 0, 0, 0);
        } else {
          accA = __builtin_amdgcn_mfma_f32_16x16x32_bf16(af[j][0], b0, accA, 0, 0, 0);
          accA = __builtin_amdgcn_mfma_f32_16x16x32_bf16(af[j][1], b1, accA, 0, 0, 0);
        }
      }
      if (colb < 400) {
        int tt = colb / 25, v = colb - tt*25, t = t0 + tt;
        #pragma unroll
        for (int r = 0; r < 4; r++) {
          int oo = o0 + grp*4 + r;
          float val = accA[r] + accB[r] + ((const float*)&cb4)[r]
                    + x[((n*64 + oo)*256 + t)*25 + v];
          out[((n*64 + oo)*256 + t)*25 + v] = fmaxf(val, 0.f);
        }
      }
    }
    if (phase == 0) __syncthreads();      // chunk 2 landed
  }
}

extern "C" void kernel_launch(void* const* d_in, const int* in_sizes, int n_in,
                              void* d_out, int out_size, void* d_ws, size_t ws_size,
                              hipStream_t stream)
{
  fp x  = (fp)d_in[0];
  fp A  = (fp)d_in[1];
  fp W  = (fp)d_in[2];
  fp b  = (fp)d_in[3];
  fp g0 = (fp)d_in[4];
  fp b0 = (fp)d_in[5];
  fp g1 = (fp)d_in[6];
  fp b1 = (fp)d_in[7];
  fp cw = (fp)d_in[8];
  fp cb = (fp)d_in[9];
  fp g2 = (fp)d_in[10];
  fp b2 = (fp)d_in[11];
  // d_in[12] = keep_prob == 1 -> DropBlocks identity.

  char* ws = (char*)d_ws;
  float*          cbe   = (float*)(ws + 117504);
  unsigned short* cwetb = (unsigned short*)(ws + 117760);
  float*          biasU = (float*)(ws + 191488);
  unsigned short* U     = (unsigned short*)(ws + 197888);
  unsigned short* xb    = (unsigned short*)(ws + 5932288);
  unsigned short* yb    = (unsigned short*)(ws + 32146688);
  const unsigned short* zpg = U + (long long)1600*1600;  // zeroed pad rows

  k_prep<<<2961, 256, 0, stream>>>(x, A, W, b, g0, b0, g1, b1, cw, cb, g2, b2,
                                   U, biasU, xb, cbe, cwetb);
  k_gemm<<<448, 512, 0, stream>>>(U, xb, biasU, yb);
  k_tcn<<<512, 512, 0, stream>>>(yb, cwetb, cbe, x, zpg, (float*)d_out);
}

// Round 16
// 200.848 us; speedup vs baseline: 1.0819x; 1.0254x over previous
//
#include <hip/hip_runtime.h>
#include <hip/hip_bf16.h>
#include <stdint.h>

// Shapes: N=32, CIN=COUT=64, T=256, V=25, K3=3, G=8
// GCN folded to one GEMM: M=1600 (m=w*64+c), K=1600 (k=cin*25+v), N=8192 (n,t)
//   residual (+x) folded into U's diagonal: U[w*64+c][c*25+w] += 1
// k_prep: FUSED (2961 blocks), xt blocks FIRST so U-phase traffic evicts
//   part of xb's dirty L2 set during prep, not during gemm (R10-confirmed).
// k_gemm (R12, session best): 256m x 128n tile, 512 threads = 8 waves,
//   2-barrier loop, BK=64, XOR-swizzled staging, conflict-free reads.
//   Failed alternatives: 8-phase (fill/L2-affinity), 128^2 (intensity),
//   32x32 MFMA + BK=32 dbuf (bank keys). bid%8 = bn%8 keeps B-panel
//   reuse XCD-local.
// k_tcn R16: TB=16, dual-acc, 2-phase staging (R9/R10) + two epilogue
//   changes: (1) residual read from xb (bf16) instead of x (fp32) — xb
//   already holds bf16(x) in [n][t][c*25+v] layout, halves residual read;
//   (2) NT store for out — write-once data; keeps 52MB of dirty lines out
//   of L2 so the NEXT iteration's prep/gemm don't pay the drain (R3/R10
//   conserved-writeback mechanism; R7/R8's NT losses were on RE-READ bufs).

typedef const float* fp;
typedef __attribute__((ext_vector_type(8))) short short8;   // 8 bf16 (4 VGPRs)
typedef __attribute__((ext_vector_type(4))) float floatx4;  // MFMA acc

__device__ __forceinline__ float us2f(unsigned int u){
  union { unsigned int i; float f; } c; c.i = u << 16; return c.f;
}
__device__ __forceinline__ unsigned short f2us(float f){
  __hip_bfloat16 h = __float2bfloat16(f);
  return *reinterpret_cast<unsigned short*>(&h);
}
__device__ __forceinline__ void gload_lds16(const void* g, void* l){
  __builtin_amdgcn_global_load_lds(
      (const __attribute__((address_space(1))) void*)g,
      (__attribute__((address_space(3))) void*)l, 16, 0, 0);
}

// ---------------- workspace layout (bytes) ----------------
// cbe   fp32 [64]           @ 117504    (256)
// cwetb bf16 [64][9][64]    @ 117760    (73728)
// biasU fp32 [1600]         @ 191488    (6400)
// U     bf16 [1792][1600]   @ 197888    (5734400)  rows 1600+ = zero page
// xb    bf16 [32][256][1600]@ 5932288   (26214400)
// yb    bf16 [32][256][1600]@ 32146688  (26214400)   total ~58.4 MB

// ---------------- fused prep ----------------
// blocks [0,1024): x -> xb bf16 transpose (FIRST: xb dirty lines get
//                  evicted/written-back during the U phase below)
// blocks [1024,2816): U row m = bid-1024 (+ biasU), pad rows zeroed
// blocks [2816,2961): cwetb (36864) + cbe (64)  (last: L2-hot for k_tcn)
__global__ __launch_bounds__(256) void k_prep(
    fp x, fp A, fp W, fp b, fp g0, fp b0, fp g1, fp b1,
    fp cw, fp cb, fp g2, fp b2,
    unsigned short* U, float* biasU, unsigned short* xb,
    float* cbe, unsigned short* cwetb)
{
  int bid = blockIdx.x, tid = threadIdx.x;
  const float inv_s = rsqrtf(1.0f + 1e-5f);
  __shared__ __align__(16) char smemraw[26624];   // union: xt needs 26 KB

  if (bid < 1024) {                     // ---- x -> xb transpose ----
    int n = bid >> 5, tb = bid & 31, t0 = tb*8;
    unsigned short* xs = (unsigned short*)smemraw;  // [64*8][26]
    // x c-slab is 200 contiguous floats (8t x 25v): float4 loads
    for (int e4 = tid; e4 < 3200; e4 += 256) {
      int c = e4 / 50, r4 = (e4 - c*50)*4;
      floatx4 xv = *(const floatx4*)(x + (long long)(n*64 + c)*6400 + t0*25 + r4);
      int tt = r4 / 25, v = r4 - tt*25;
      xs[(c*8 + tt)*26 + v] = f2us(xv.x); if (++v == 25){v = 0; tt++;}
      xs[(c*8 + tt)*26 + v] = f2us(xv.y); if (++v == 25){v = 0; tt++;}
      xs[(c*8 + tt)*26 + v] = f2us(xv.z); if (++v == 25){v = 0; tt++;}
      xs[(c*8 + tt)*26 + v] = f2us(xv.w);
    }
    __syncthreads();
    for (int e4 = tid; e4 < 3200; e4 += 256) {      // ushort4 stores
      int base = e4 * 4;
      int tt = base / 1600, q0 = base - tt*1600;
      int c = q0 / 25, v = q0 - c*25;
      ushort4 pk;
      pk.x = xs[(c*8 + tt)*26 + v]; if (++v == 25){v = 0; c++;}
      pk.y = xs[(c*8 + tt)*26 + v]; if (++v == 25){v = 0; c++;}
      pk.z = xs[(c*8 + tt)*26 + v]; if (++v == 25){v = 0; c++;}
      pk.w = xs[(c*8 + tt)*26 + v];
      *(ushort4*)(xb + (long long)(n*256 + t0 + tt)*1600 + q0) = pk;
    }
    return;
  }

  if (bid < 2816) {                     // ---- U rows ----
    int m = bid - 1024;
    if (m >= 1600) {                    // zero-pad rows (k_tcn zero page)
      if (tid < 200) {
        short8 z = (short8){0,0,0,0,0,0,0,0};
        *(short8*)(U + (long long)m*1600 + tid*8) = z;
      }
      return;
    }
    float* nAL   = (float*)smemraw;          // 75 floats
    float* WeffL = (float*)(smemraw + 512);  // 192 floats
    float* cs3   = (float*)(smemraw + 1408); // 3 floats
    int c = m & 63, w = m >> 6, g = c & 7;
    if (tid < 75) {                     // raw A column w for (kk,g)
      int kk = tid / 25, vv = tid % 25;
      nAL[tid] = A[((kk*8 + g)*25 + vv)*25 + w];
    }
    if (tid < 192) {                    // W col c scaled by folded BN0 gain
      int kk = tid >> 6, cin = tid & 63;
      WeffL[tid] = W[cin*192 + kk*64 + c] * (g0[kk*64 + c] * inv_s);
    }
    __syncthreads();
    if (tid < 3) {                      // column sums -> denominators
      float s = 0.f;
      for (int vv = 0; vv < 25; vv++) s += nAL[tid*25 + vv];
      cs3[tid] = s + 0.001f;
    }
    __syncthreads();
    if (tid < 75) nAL[tid] = nAL[tid] / cs3[tid/25];
    __syncthreads();
    float s1 = g1[c] * inv_s;
    if (tid < 200) {                    // 8 consecutive k per thread
      int k0 = tid * 8;
      short8 pk;
      #pragma unroll
      for (int q = 0; q < 8; q++) {
        int k = k0 + q;
        int cin = k / 25, vv = k - cin*25;
        float acc = WeffL[cin]       * nAL[vv]
                  + WeffL[64 + cin]  * nAL[25 + vv]
                  + WeffL[128 + cin] * nAL[50 + vv];
        acc *= s1;
        if (cin == c && vv == w) acc += 1.0f;  // residual -> diagonal
        pk[q] = (short)f2us(acc);
      }
      *(short8*)(U + (long long)m*1600 + k0) = pk;
    }
    if (tid == 0) {
      float acc = 0.f;
      for (int kk = 0; kk < 3; kk++) {
        int d = kk*64 + c;
        float be = b[d] * (g0[d] * inv_s) + b0[d];
        for (int v = 0; v < 25; v++) acc += be * nAL[kk*25 + v];
      }
      biasU[m] = acc * s1 + b1[c];
    }
    return;
  }

  // ---- cwetb + cbe tail ----
  int gid = (bid - 2816)*256 + tid;
  if (gid < 36864) {                    // cwetb[o][j][i] bf16
    int o = gid / 576, r = gid % 576;
    int j = r / 64, i = r % 64;
    cwetb[gid] = f2us(cw[(o*64+i)*9 + j] * (g2[o] * inv_s));
    return;
  }
  gid -= 36864;
  if (gid < 64) {                       // cbe
    cbe[gid] = cb[gid] * (g2[gid] * inv_s) + b2[gid];
  }
}

// ---------------- GCN GEMM: 256m x 128n, 8 waves (R12, session best) -----
// 448 blocks (7 bm x 64 bn), 512 threads = 8 waves, wave owns 32m x 128n.
// 48KB LDS -> 2 blocks/CU, ~16 waves/CU hide the 2-barrier drain (m114).
__global__ __launch_bounds__(512, 4) void k_gemm(
    const unsigned short* U, const unsigned short* xb, const float* biasU,
    unsigned short* yb)
{
  int bm = blockIdx.x >> 6, bn = blockIdx.x & 63;   // 7 x 64
  int n = bn >> 1, t0 = (bn & 1) * 128;
  int tid = threadIdx.x, lane = tid & 63, wid = tid >> 6;
  int l15 = lane & 15, grp = lane >> 4;

  __shared__ __align__(16) unsigned short As[256*64];  // 32 KB
  __shared__ __align__(16) unsigned short Bs[128*64];  // 16 KB

  const unsigned short* gA[4];
  const unsigned short* gB[2];
  unsigned short* lA[4];
  unsigned short* lB[2];
  #pragma unroll
  for (int it = 0; it < 4; it++) {
    int e = it*512 + tid;
    int row = e >> 3, li = e & 7;
    int kcol = (li ^ (row & 7)) * 8;       // XOR swizzle on global source side
    gA[it] = U + (long long)(bm*256 + row)*1600 + kcol;
    lA[it] = As + e*8;
  }
  #pragma unroll
  for (int it = 0; it < 2; it++) {
    int e = it*512 + tid;
    int row = e >> 3, li = e & 7;
    int kcol = (li ^ (row & 7)) * 8;
    gB[it] = xb + (long long)(n*256 + t0 + row)*1600 + kcol;
    lB[it] = Bs + e*8;
  }

  floatx4 acc[2][8];
  #pragma unroll
  for (int i = 0; i < 2; i++)
    #pragma unroll
    for (int j = 0; j < 8; j++) acc[i][j] = (floatx4){0.f,0.f,0.f,0.f};

  for (int kc = 0; kc < 25; kc++) {
    #pragma unroll
    for (int it = 0; it < 4; it++) gload_lds16(gA[it] + kc*64, lA[it]);
    #pragma unroll
    for (int it = 0; it < 2; it++) gload_lds16(gB[it] + kc*64, lB[it]);
    __syncthreads();
    #pragma unroll
    for (int ks = 0; ks < 2; ks++) {
      int colk = ((ks*4 + grp) ^ (l15 & 7)) * 8;   // un-swizzle at read
      short8 af[2], bf[8];
      #pragma unroll
      for (int i = 0; i < 2; i++)
        af[i] = *(const short8*)(As + (wid*32 + i*16 + l15)*64 + colk);
      #pragma unroll
      for (int j = 0; j < 8; j++)
        bf[j] = *(const short8*)(Bs + (j*16 + l15)*64 + colk);
      #pragma unroll
      for (int i = 0; i < 2; i++)
        #pragma unroll
        for (int j = 0; j < 8; j++)
          acc[i][j] = __builtin_amdgcn_mfma_f32_16x16x32_bf16(af[i], bf[j], acc[i][j], 0, 0, 0);
    }
    __syncthreads();
  }

  #pragma unroll
  for (int i = 0; i < 2; i++) {
    int mbase = bm*256 + wid*32 + i*16 + grp*4;
    if (mbase >= 1600) continue;
    float4 bu = *(const float4*)(biasU + mbase);
    #pragma unroll
    for (int j = 0; j < 8; j++) {
      int col = j*16 + l15;
      int t = t0 + col;
      ushort4 pk;
      pk.x = f2us(fmaxf(acc[i][j][0] + bu.x, 0.f));
      pk.y = f2us(fmaxf(acc[i][j][1] + bu.y, 0.f));
      pk.z = f2us(fmaxf(acc[i][j][2] + bu.z, 0.f));
      pk.w = f2us(fmaxf(acc[i][j][3] + bu.w, 0.f));
      *(ushort4*)(yb + (long long)(n*256 + t)*1600 + mbase) = pk;
    }
  }
}

// ---------------- TCN as MFMA: TB=16, 512 blocks, dual-acc, 2-phase ------
// 8 waves share one 80 KB window (600 rows = 24t x 25v, pad to 640);
// wave pair (p, p+4) owns o-strip p*16 and splits the 25 col-tiles
// even/odd. Staging via global_load_lds; OOB rows from zpg.
// Phase split: stage rows<384 -> barrier -> issue rows 384-639 + compute
// tiles 0-10 (max row 375, disjoint from in-flight DMA) -> barrier ->
// tiles 11-24. Dual accumulators halve the MFMA dep chain.
// R16: residual from xb (bf16, half the bytes of x fp32); NT store on out.
__global__ __launch_bounds__(512) void k_tcn(
    const unsigned short* yb, const unsigned short* cwetb, const float* cbe,
    const unsigned short* xb, const unsigned short* zpg, float* out)
{
  int n = blockIdx.x >> 4, tb = blockIdx.x & 15, t0 = tb*16;
  int tid = threadIdx.x, lane = tid & 63, wid = tid >> 6;
  int l15 = lane & 15, grp = lane >> 4;
  __shared__ __align__(16) unsigned short ys[5120*8];  // 81920 B (600 rows + pad)

  #pragma unroll
  for (int it = 0; it < 6; it++) {        // chunk 1: rows < 384
    int e = it*512 + tid;
    int row = e >> 3, li = e & 7;
    int rt = row / 25, v = row - rt*25;
    int tg = t0 - 4 + rt;
    int sli = li ^ (row & 7);             // fetch swizzled i-group
    bool ok = (tg >= 0) && (tg < 256);
    const unsigned short* src = ok
      ? yb + ((long long)(n*256 + tg)*1600 + v*64 + sli*8)
      : zpg + li*8;
    gload_lds16(src, ys + e*8);           // linear LDS deposit
  }

  // A-frags: conv weights in registers, o-strip p = wid&3, half h = wid>>2
  int p = wid & 3, h = wid >> 2;
  int o0 = p * 16;
  int o = o0 + l15;
  short8 af[9][2];
  #pragma unroll
  for (int j = 0; j < 9; j++) {
    af[j][0] = *(const short8*)(cwetb + ((o*9 + j)*64 + grp*8));
    af[j][1] = *(const short8*)(cwetb + ((o*9 + j)*64 + 32 + grp*8));
  }
  float4 cb4 = *(const float4*)(cbe + o0 + grp*4);
  __syncthreads();                        // chunk 1 landed

  #pragma unroll
  for (int it = 6; it < 10; it++) {       // chunk 2: rows 384-639 (in flight)
    int e = it*512 + tid;
    int row = e >> 3, li = e & 7;
    int rt = row / 25, v = row - rt*25;
    int tg = t0 - 4 + rt;
    int sli = li ^ (row & 7);
    bool ok = (row < 600) && (tg >= 0) && (tg < 256);
    const unsigned short* src = ok
      ? yb + ((long long)(n*256 + tg)*1600 + v*64 + sli*8)
      : zpg + li*8;
    gload_lds16(src, ys + e*8);
  }

  #pragma unroll 1
  for (int phase = 0; phase < 2; phase++) {
    int tstart = phase ? (12 - h) : h;    // phase0: tiles<=10; phase1: 11-24
    int tend   = phase ? 25 : 11;
    for (int tile = tstart; tile < tend; tile += 2) {
      int colb = tile*16 + l15;
      floatx4 accA = (floatx4){0.f,0.f,0.f,0.f};
      floatx4 accB = (floatx4){0.f,0.f,0.f,0.f};
      #pragma unroll
      for (int j = 0; j < 9; j++) {
        int row = colb + 25*j;
        int r7 = row & 7;
        const unsigned short* rb = ys + row*64;
        short8 b0 = *(const short8*)(rb + ((grp     ^ r7))*8);
        short8 b1 = *(const short8*)(rb + (((4+grp) ^ r7))*8);
        if (j & 1) {
          accB = __builtin_amdgcn_mfma_f32_16x16x32_bf16(af[j][0], b0, accB, 0, 0, 0);
          accB = __builtin_amdgcn_mfma_f32_16x16x32_bf16(af[j][1], b1, accB, 0, 0, 0);
        } else {
          accA = __builtin_amdgcn_mfma_f32_16x16x32_bf16(af[j][0], b0, accA, 0, 0, 0);
          accA = __builtin_amdgcn_mfma_f32_16x16x32_bf16(af[j][1], b1, accA, 0, 0, 0);
        }
      }
      if (colb < 400) {
        int tt = colb / 25, v = colb - tt*25, t = t0 + tt;
        const unsigned short* xrow = xb + (long long)(n*256 + t)*1600 + v;
        #pragma unroll
        for (int r = 0; r < 4; r++) {
          int oo = o0 + grp*4 + r;
          float val = accA[r] + accB[r] + ((const float*)&cb4)[r]
                    + us2f(xrow[oo*25]);
          __builtin_nontemporal_store(fmaxf(val, 0.f),
              out + ((long long)(n*64 + oo)*256 + t)*25 + v);
        }
      }
    }
    if (phase == 0) __syncthreads();      // chunk 2 landed
  }
}

extern "C" void kernel_launch(void* const* d_in, const int* in_sizes, int n_in,
                              void* d_out, int out_size, void* d_ws, size_t ws_size,
                              hipStream_t stream)
{
  fp x  = (fp)d_in[0];
  fp A  = (fp)d_in[1];
  fp W  = (fp)d_in[2];
  fp b  = (fp)d_in[3];
  fp g0 = (fp)d_in[4];
  fp b0 = (fp)d_in[5];
  fp g1 = (fp)d_in[6];
  fp b1 = (fp)d_in[7];
  fp cw = (fp)d_in[8];
  fp cb = (fp)d_in[9];
  fp g2 = (fp)d_in[10];
  fp b2 = (fp)d_in[11];
  // d_in[12] = keep_prob == 1 -> DropBlocks identity.

  char* ws = (char*)d_ws;
  float*          cbe   = (float*)(ws + 117504);
  unsigned short* cwetb = (unsigned short*)(ws + 117760);
  float*          biasU = (float*)(ws + 191488);
  unsigned short* U     = (unsigned short*)(ws + 197888);
  unsigned short* xb    = (unsigned short*)(ws + 5932288);
  unsigned short* yb    = (unsigned short*)(ws + 32146688);
  const unsigned short* zpg = U + (long long)1600*1600;  // zeroed pad rows

  k_prep<<<2961, 256, 0, stream>>>(x, A, W, b, g0, b0, g1, b1, cw, cb, g2, b2,
                                   U, biasU, xb, cbe, cwetb);
  k_gemm<<<448, 512, 0, stream>>>(U, xb, biasU, yb);
  k_tcn<<<512, 512, 0, stream>>>(yb, cwetb, cbe, xb, zpg, (float*)d_out);
}